// Round 10
// baseline (157.642 us; speedup 1.0000x reference)
//
#include <hip/hip_runtime.h>
#include <hip/hip_bf16.h>

// R10 = R9 (MFMA GEMM, dwordx4 streams) run TWICE internally.
// DIAGNOSTIC ROUND: the harness's ~155us poison-fill dispatches crowd our
// ~94us kernel out of the top-5 counter table; doubling the work pushes one
// dispatch to ~190us so FETCH/WRITE/VALUBusy/MfmaUtil become visible.
// Pass 2 recomputes and rewrites identical values -> deterministic, same
// final output. Next round reverts to single-pass and acts on the counters.
//
//   C[32 x 1M] = P[32 x 64] @ W[64 x 1M]   (W = wbank viewed [E, O*I])
// v_mfma_f32_32x32x16_bf16 + split compensation (Ph*Wh + Ph*Wl + Pl*Wh).
// Layouts verified R6-R9 (absmax 9.8e-4 vs 4.57e-3 threshold).

typedef __attribute__((ext_vector_type(8)))  short short8v;
typedef __attribute__((ext_vector_type(16))) float f32x16;

constexpr int E = 64;
constexpr int K = 8;
constexpr int B = 32;
constexpr int IN_DIM = 1024;
constexpr int OUT_DIM = 1024;

constexpr int NCOL     = OUT_DIM * IN_DIM;    // 1,048,576
constexpr int BLK      = 256;
constexpr int GRID     = 512;                 // 2 blocks/CU, single round
constexpr int WAVES    = GRID * 4;            // 2048
constexpr int CPW      = NCOL / WAVES;        // 512 cols per wave
constexpr int CSTEP    = 128;                 // cols per step
constexpr int STEPS    = CPW / CSTEP;         // 4
constexpr int NRG      = STEPS * 4;           // 16 rowgroups per wave
constexpr int WM_ELEMS = B * NCOL;
constexpr int OB4      = OUT_DIM / 4;         // 256

struct HL { short h; short l; };

__device__ __forceinline__ HL split_bf16(float x) {
    const __hip_bfloat16 hb = __float2bfloat16(x);
    const float          hf = __bfloat162float(hb);
    const __hip_bfloat16 lb = __float2bfloat16(x - hf);
    HL r;
    r.h = __builtin_bit_cast(short, hb);
    r.l = __builtin_bit_cast(short, lb);
    return r;
}

__global__ __launch_bounds__(BLK, 2) void ParameterMixture_86835648790543_kernel(
    const float* __restrict__ wprobs,   // [B,K]
    const float* __restrict__ bprobs,   // [B,K]
    const int*   __restrict__ widx,     // [B,K]
    const int*   __restrict__ bidx,     // [B,K]
    const float* __restrict__ wbank,    // [E, NCOL]
    const float* __restrict__ bbank,    // [E,O]
    float*       __restrict__ out)      // [B*NCOL] ++ [B*O]
{
    const int bid  = blockIdx.x;
    const int t    = threadIdx.x;
    const int wv   = t >> 6;
    const int lane = t & 63;
    const int m    = lane & 31;         // A row (batch)
    const int kh   = (lane >> 5) * 8;   // k half-offset
    const int cl   = lane & 31;         // column-group index

    // ---- bias prologue on blocks 0..31 (tiny, fp32 exact) ----
    if (bid < 32) {
        const int tt   = bid * BLK + t;
        const int b    = tt / OB4;
        const int off4 = tt % OB4;
        const float4* __restrict__ bb4 = (const float4*)bbank;
        float4 a4 = make_float4(0.f, 0.f, 0.f, 0.f);
#pragma unroll
        for (int k = 0; k < K; ++k) {
            const float p = bprobs[b * K + k];
            const int   e = bidx[b * K + k];
            const float4 v = bb4[e * OB4 + off4];
            a4.x += p * v.x; a4.y += p * v.y;
            a4.z += p * v.z; a4.w += p * v.w;
        }
        ((float4*)(out + WM_ELEMS))[tt] = a4;
    }

    // ---- per-lane A-fragments (P in bf16 hi/lo, MFMA layout) ----
    float wp[K];
    int   wi[K];
#pragma unroll
    for (int k2 = 0; k2 < K; ++k2) {
        wp[k2] = wprobs[m * K + k2];
        wi[k2] = widx[m * K + k2];
    }
    short8v aH[4], aL[4];
#pragma unroll
    for (int s = 0; s < 4; ++s) {
#pragma unroll
        for (int j = 0; j < 8; ++j) {
            const int e = s * 16 + kh + j;
            float p = 0.f;
#pragma unroll
            for (int k2 = 0; k2 < K; ++k2)
                p += (wi[k2] == e) ? wp[k2] : 0.f;
            const HL r = split_bf16(p);
            aH[s][j] = r.h;
            aL[s][j] = r.l;
        }
    }

    const size_t ncol     = (size_t)NCOL;
    const int    wave_id  = bid * 4 + wv;
    const int    col_base = wave_id * CPW;

    auto load_rg = [&](float4 (&w)[8], int g) {
        if (g > NRG - 1) g = NRG - 1;                 // tail clamp
        const int c0 = col_base + (g >> 2) * CSTEP + 4 * cl;
        const int r0 = (g & 3) * 16 + kh;
        const float* __restrict__ base = wbank + c0;
#pragma unroll
        for (int j = 0; j < 8; ++j)
            w[j] = *(const float4*)(base + (size_t)(r0 + j) * ncol);
    };

    // ==== DIAGNOSTIC: full work twice (idempotent; see header comment) ====
#pragma unroll 1
    for (int pass = 0; pass < 2; ++pass) {
        float4 bufA[8], bufB[8];
        load_rg(bufA, 0);
        load_rg(bufB, 1);

#pragma unroll 1
        for (int step = 0; step < STEPS; ++step) {
            f32x16 acc[4];
#pragma unroll
            for (int tt2 = 0; tt2 < 4; ++tt2)
#pragma unroll
                for (int i = 0; i < 16; ++i) acc[tt2][i] = 0.f;

            const int g0 = step * 4;

            auto compute_rg = [&](const float4 (&w)[8], int rg) {
                short8v bh[4], bl[4];
#pragma unroll
                for (int j = 0; j < 8; ++j) {
                    const HL rx = split_bf16(w[j].x);
                    const HL ry = split_bf16(w[j].y);
                    const HL rz = split_bf16(w[j].z);
                    const HL rw = split_bf16(w[j].w);
                    bh[0][j] = rx.h; bl[0][j] = rx.l;
                    bh[1][j] = ry.h; bl[1][j] = ry.l;
                    bh[2][j] = rz.h; bl[2][j] = rz.l;
                    bh[3][j] = rw.h; bl[3][j] = rw.l;
                }
#pragma unroll
                for (int tt2 = 0; tt2 < 4; ++tt2) {
                    acc[tt2] = __builtin_amdgcn_mfma_f32_32x32x16_bf16(aH[rg], bh[tt2], acc[tt2], 0, 0, 0);
                    acc[tt2] = __builtin_amdgcn_mfma_f32_32x32x16_bf16(aH[rg], bl[tt2], acc[tt2], 0, 0, 0);
                    acc[tt2] = __builtin_amdgcn_mfma_f32_32x32x16_bf16(aL[rg], bh[tt2], acc[tt2], 0, 0, 0);
                }
            };

            compute_rg(bufA, 0);  load_rg(bufA, g0 + 2);
            compute_rg(bufB, 1);  load_rg(bufB, g0 + 3);
            compute_rg(bufA, 2);  load_rg(bufA, g0 + 4);
            compute_rg(bufB, 3);  load_rg(bufB, g0 + 5);

            const int c0 = col_base + step * CSTEP + 4 * cl;
            float* __restrict__ ob = out + c0 + (size_t)((lane >> 5) * 4) * ncol;
#pragma unroll
            for (int reg = 0; reg < 16; ++reg) {
                const int row = (reg & 3) + 8 * (reg >> 2);
                const float4 v = make_float4(acc[0][reg], acc[1][reg], acc[2][reg], acc[3][reg]);
                *(float4*)(ob + (size_t)row * ncol) = v;
            }
        }
    }
}

extern "C" void kernel_launch(void* const* d_in, const int* in_sizes, int n_in,
                              void* d_out, int out_size, void* d_ws, size_t ws_size,
                              hipStream_t stream) {
    const float* wprobs = (const float*)d_in[0];
    const float* bprobs = (const float*)d_in[1];
    const int*   widx   = (const int*)d_in[2];
    const int*   bidx   = (const int*)d_in[3];
    const float* wbank  = (const float*)d_in[4];
    const float* bbank  = (const float*)d_in[5];
    float*       out    = (float*)d_out;

    ParameterMixture_86835648790543_kernel<<<GRID, BLK, 0, stream>>>(
        wprobs, bprobs, widx, bidx, wbank, bbank, out);
}

// Round 11
// 116.618 us; speedup vs baseline: 1.3518x; 1.3518x over previous
//
#include <hip/hip_runtime.h>
#include <hip/hip_bf16.h>

// ParameterMixture as a thin GEMM on matrix cores, dwordx4 streams.
//   C[32 x 1M] = P[32 x 64] @ W[64 x 1M]   (W = wbank viewed [E, O*I])
// v_mfma_f32_32x32x16_bf16 + split compensation (Ph*Wh + Ph*Wl + Pl*Wh),
// layouts verified R6-R10 (absmax 9.8e-4 vs 4.57e-3 threshold).
//
// R11: occupancy fix. R10 diagnostic counters: hbm 34%, VALU 10%, MFMA 5%,
// Occupancy 20.7% -> latency/MLP-bound at 2 blocks/CU. This round: GRID=1024
// = 4 blocks/CU exactly (128 VGPR = 4 waves/SIMD fits), doubling outstanding
// requests per CU. True HBM traffic ~258 MB (L3 absorbs ~half of wbank reads;
// R10: FETCH 254 MB for TWO passes) -> roofline ~42us.
//
// Layouts (gfx950, 32x32x16 bf16):
//   A: row = lane&31, k = 8*(lane>>5)+j       B: col = lane&31, same k
//   C: col = lane&31, row = (reg&3) + 8*(reg>>2) + 4*(lane>>5)

typedef __attribute__((ext_vector_type(8)))  short short8v;
typedef __attribute__((ext_vector_type(16))) float f32x16;

constexpr int E = 64;
constexpr int K = 8;
constexpr int B = 32;
constexpr int IN_DIM = 1024;
constexpr int OUT_DIM = 1024;

constexpr int NCOL     = OUT_DIM * IN_DIM;    // 1,048,576
constexpr int BLK      = 256;
constexpr int GRID     = 1024;                // 4 blocks/CU, single round
constexpr int WAVES    = GRID * 4;            // 4096
constexpr int CPW      = NCOL / WAVES;        // 256 cols per wave
constexpr int CSTEP    = 128;                 // cols per step (4 tiles x 32)
constexpr int STEPS    = CPW / CSTEP;         // 2
constexpr int NRG      = STEPS * 4;           // 8 rowgroups per wave
constexpr int WM_ELEMS = B * NCOL;
constexpr int OB4      = OUT_DIM / 4;         // 256

struct HL { short h; short l; };

__device__ __forceinline__ HL split_bf16(float x) {
    const __hip_bfloat16 hb = __float2bfloat16(x);
    const float          hf = __bfloat162float(hb);
    const __hip_bfloat16 lb = __float2bfloat16(x - hf);
    HL r;
    r.h = __builtin_bit_cast(short, hb);
    r.l = __builtin_bit_cast(short, lb);
    return r;
}

__global__ __launch_bounds__(BLK, 4) void ParameterMixture_86835648790543_kernel(
    const float* __restrict__ wprobs,   // [B,K]
    const float* __restrict__ bprobs,   // [B,K]
    const int*   __restrict__ widx,     // [B,K]
    const int*   __restrict__ bidx,     // [B,K]
    const float* __restrict__ wbank,    // [E, NCOL]
    const float* __restrict__ bbank,    // [E,O]
    float*       __restrict__ out)      // [B*NCOL] ++ [B*O]
{
    const int bid  = blockIdx.x;
    const int t    = threadIdx.x;
    const int wv   = t >> 6;
    const int lane = t & 63;
    const int m    = lane & 31;         // A row (batch)
    const int kh   = (lane >> 5) * 8;   // k half-offset
    const int cl   = lane & 31;         // column-group index

    // ---- bias prologue on blocks 0..31 (tiny, fp32 exact) ----
    if (bid < 32) {
        const int tt   = bid * BLK + t;
        const int b    = tt / OB4;
        const int off4 = tt % OB4;
        const float4* __restrict__ bb4 = (const float4*)bbank;
        float4 a4 = make_float4(0.f, 0.f, 0.f, 0.f);
#pragma unroll
        for (int k = 0; k < K; ++k) {
            const float p = bprobs[b * K + k];
            const int   e = bidx[b * K + k];
            const float4 v = bb4[e * OB4 + off4];
            a4.x += p * v.x; a4.y += p * v.y;
            a4.z += p * v.z; a4.w += p * v.w;
        }
        ((float4*)(out + WM_ELEMS))[tt] = a4;
    }

    // ---- per-lane A-fragments (P in bf16 hi/lo, MFMA layout) ----
    float wp[K];
    int   wi[K];
#pragma unroll
    for (int k2 = 0; k2 < K; ++k2) {
        wp[k2] = wprobs[m * K + k2];
        wi[k2] = widx[m * K + k2];
    }
    short8v aH[4], aL[4];
#pragma unroll
    for (int s = 0; s < 4; ++s) {
#pragma unroll
        for (int j = 0; j < 8; ++j) {
            const int e = s * 16 + kh + j;
            float p = 0.f;
#pragma unroll
            for (int k2 = 0; k2 < K; ++k2)
                p += (wi[k2] == e) ? wp[k2] : 0.f;
            const HL r = split_bf16(p);
            aH[s][j] = r.h;
            aL[s][j] = r.l;
        }
    }

    const size_t ncol     = (size_t)NCOL;
    const int    wave_id  = bid * 4 + wv;
    const int    col_base = wave_id * CPW;

    // rowgroup g (0..NRG-1): step = g>>2, rows (g&3)*16 + kh + j, 8 float4 loads
    auto load_rg = [&](float4 (&w)[8], int g) {
        if (g > NRG - 1) g = NRG - 1;                 // tail clamp (harmless)
        const int c0 = col_base + (g >> 2) * CSTEP + 4 * cl;
        const int r0 = (g & 3) * 16 + kh;
        const float* __restrict__ base = wbank + c0;
#pragma unroll
        for (int j = 0; j < 8; ++j)
            w[j] = *(const float4*)(base + (size_t)(r0 + j) * ncol);
    };

    float4 bufA[8], bufB[8];
    load_rg(bufA, 0);
    load_rg(bufB, 1);

#pragma unroll 1
    for (int step = 0; step < STEPS; ++step) {
        f32x16 acc[4];
#pragma unroll
        for (int tt2 = 0; tt2 < 4; ++tt2)
#pragma unroll
            for (int i = 0; i < 16; ++i) acc[tt2][i] = 0.f;

        const int g0 = step * 4;

        // one rowgroup: cvt 32 floats -> 4 tiles' bh/bl, then 12 MFMA
        auto compute_rg = [&](const float4 (&w)[8], int rg) {
            short8v bh[4], bl[4];
#pragma unroll
            for (int j = 0; j < 8; ++j) {
                const HL rx = split_bf16(w[j].x);
                const HL ry = split_bf16(w[j].y);
                const HL rz = split_bf16(w[j].z);
                const HL rw = split_bf16(w[j].w);
                bh[0][j] = rx.h; bl[0][j] = rx.l;
                bh[1][j] = ry.h; bl[1][j] = ry.l;
                bh[2][j] = rz.h; bl[2][j] = rz.l;
                bh[3][j] = rw.h; bl[3][j] = rw.l;
            }
#pragma unroll
            for (int tt2 = 0; tt2 < 4; ++tt2) {
                acc[tt2] = __builtin_amdgcn_mfma_f32_32x32x16_bf16(aH[rg], bh[tt2], acc[tt2], 0, 0, 0);
                acc[tt2] = __builtin_amdgcn_mfma_f32_32x32x16_bf16(aH[rg], bl[tt2], acc[tt2], 0, 0, 0);
                acc[tt2] = __builtin_amdgcn_mfma_f32_32x32x16_bf16(aL[rg], bh[tt2], acc[tt2], 0, 0, 0);
            }
        };

        compute_rg(bufA, 0);  load_rg(bufA, g0 + 2);
        compute_rg(bufB, 1);  load_rg(bufB, g0 + 3);
        compute_rg(bufA, 2);  load_rg(bufA, g0 + 4);   // next step's rg0
        compute_rg(bufB, 3);  load_rg(bufB, g0 + 5);   // next step's rg1

        // store: lane cl holds cols c0+4cl..+3 of each row in its 4 accs
        const int c0 = col_base + step * CSTEP + 4 * cl;
        float* __restrict__ ob = out + c0 + (size_t)((lane >> 5) * 4) * ncol;
#pragma unroll
        for (int reg = 0; reg < 16; ++reg) {
            const int row = (reg & 3) + 8 * (reg >> 2);
            const float4 v = make_float4(acc[0][reg], acc[1][reg], acc[2][reg], acc[3][reg]);
            *(float4*)(ob + (size_t)row * ncol) = v;
        }
    }
}

extern "C" void kernel_launch(void* const* d_in, const int* in_sizes, int n_in,
                              void* d_out, int out_size, void* d_ws, size_t ws_size,
                              hipStream_t stream) {
    const float* wprobs = (const float*)d_in[0];
    const float* bprobs = (const float*)d_in[1];
    const int*   widx   = (const int*)d_in[2];
    const int*   bidx   = (const int*)d_in[3];
    const float* wbank  = (const float*)d_in[4];
    const float* bbank  = (const float*)d_in[5];
    float*       out    = (float*)d_out;

    ParameterMixture_86835648790543_kernel<<<GRID, BLK, 0, stream>>>(
        wprobs, bprobs, widx, bidx, wbank, bbank, out);
}

// Round 12
// 105.470 us; speedup vs baseline: 1.4947x; 1.1057x over previous
//
#include <hip/hip_runtime.h>
#include <hip/hip_bf16.h>

// ParameterMixture = thin GEMM C[32 x 1M] = P[32x64] @ W[64 x 1M], MFMA bf16
// split-compensated (Ph*Wh + Ph*Wl + Pl*Wh), layouts verified R6-R11.
//
// R12: LDS-staged streaming. Evidence (R10/R11): latency/stream-bound, NOT
// BW-bound (L3-pass == HBM-pass speed, all pipes <11%, more TLP hurts).
// Old pattern interleaved ~96 distinct 4MB-strided streams per wave at
// instruction granularity. New pattern: global_load_lds stages [64x128]
// tiles ROW-BY-ROW (each staging instr = 2 sequential 512B row-pieces),
// double-buffered with counted vmcnt(8) (prefetch never drained, T4),
// raw s_barrier. MFMA B-fragments via conflict-free ds_read_b32.
// Each block owns 2048 contiguous cols -> 16 tiles; writes advance
// sequentially per block. GRID=512 (2 blocks/CU by 64KB LDS).

typedef __attribute__((ext_vector_type(8)))  short short8v;
typedef __attribute__((ext_vector_type(16))) float f32x16;

constexpr int E = 64;
constexpr int K = 8;
constexpr int B = 32;
constexpr int OUT_DIM = 1024;

constexpr int NCOL     = 1024 * 1024;        // W cols
constexpr int BLK      = 256;
constexpr int GRID     = 512;                // 2 blocks/CU, single round
constexpr int TCOLS    = 128;                // cols per LDS tile
constexpr int TILES    = 16;                 // tiles per block
constexpr int CPB      = TCOLS * TILES;      // 2048 cols per block
constexpr int WM_ELEMS = B * NCOL;
constexpr int OB4      = OUT_DIM / 4;        // 256

#define AS1C(p) ((const __attribute__((address_space(1))) void*)(p))
#define AS3(p)  ((__attribute__((address_space(3))) void*)(p))

struct HL { short h; short l; };

__device__ __forceinline__ HL split_bf16(float x) {
    const __hip_bfloat16 hb = __float2bfloat16(x);
    const float          hf = __bfloat162float(hb);
    const __hip_bfloat16 lb = __float2bfloat16(x - hf);
    HL r;
    r.h = __builtin_bit_cast(short, hb);
    r.l = __builtin_bit_cast(short, lb);
    return r;
}

__global__ __launch_bounds__(BLK, 2) void ParameterMixture_86835648790543_kernel(
    const float* __restrict__ wprobs,   // [B,K]
    const float* __restrict__ bprobs,   // [B,K]
    const int*   __restrict__ widx,     // [B,K]
    const int*   __restrict__ bidx,     // [B,K]
    const float* __restrict__ wbank,    // [E, NCOL]
    const float* __restrict__ bbank,    // [E,O]
    float*       __restrict__ out)      // [B*NCOL] ++ [B*O]
{
    __shared__ float sT[2][64][TCOLS];  // 64 KB, double-buffered

    const int bid  = blockIdx.x;
    const int t    = threadIdx.x;
    const int wv   = t >> 6;
    const int lane = t & 63;
    const int m    = lane & 31;         // A row (batch)
    const int kh   = (lane >> 5) * 8;   // k half-offset
    const int cl   = lane & 31;         // column index within 32-group

    // ---- bias prologue on blocks 0..31 (tiny, fp32 exact) ----
    if (bid < 32) {
        const int tt   = bid * BLK + t;
        const int b    = tt / OB4;
        const int off4 = tt % OB4;
        const float4* __restrict__ bb4 = (const float4*)bbank;
        float4 a4 = make_float4(0.f, 0.f, 0.f, 0.f);
#pragma unroll
        for (int k = 0; k < K; ++k) {
            const float p = bprobs[b * K + k];
            const int   e = bidx[b * K + k];
            const float4 v = bb4[e * OB4 + off4];
            a4.x += p * v.x; a4.y += p * v.y;
            a4.z += p * v.z; a4.w += p * v.w;
        }
        ((float4*)(out + WM_ELEMS))[tt] = a4;
    }

    // ---- per-lane A-fragments (P in bf16 hi/lo, MFMA layout) ----
    float wp[K];
    int   wi[K];
#pragma unroll
    for (int k2 = 0; k2 < K; ++k2) {
        wp[k2] = wprobs[m * K + k2];
        wi[k2] = widx[m * K + k2];
    }
    short8v aH[4], aL[4];
#pragma unroll
    for (int s = 0; s < 4; ++s) {
#pragma unroll
        for (int j = 0; j < 8; ++j) {
            const int e = s * 16 + kh + j;
            float p = 0.f;
#pragma unroll
            for (int k2 = 0; k2 < K; ++k2)
                p += (wi[k2] == e) ? wp[k2] : 0.f;
            const HL r = split_bf16(p);
            aH[s][j] = r.h;
            aL[s][j] = r.l;
        }
    }

    const size_t ncol   = (size_t)NCOL;
    const int    c_base = bid * CPB;

    // ---- stage tile i into buffer buf: 8 x global_load_lds(16B) per wave ----
    // Round r: wave wv covers LDS bytes [r*4096 + wv*1024, +1024) (HW adds
    // lane*16), i.e. rows r*8 + 2*wv + lane/32, cols 4*(lane&31)..+3.
    auto stage = [&](int buf, int i) {
        const int c0 = c_base + i * TCOLS;
        char* lds_base = (char*)&sT[buf][0][0];
#pragma unroll
        for (int r = 0; r < 8; ++r) {
            const int row = r * 8 + 2 * wv + (lane >> 5);
            const float* src = wbank + (size_t)row * ncol + c0 + (lane & 31) * 4;
            __builtin_amdgcn_global_load_lds(
                (const __attribute__((address_space(1))) unsigned int*)AS1C(src),
                (__attribute__((address_space(3))) unsigned int*)AS3(lds_base + r * 4096 + wv * 1024),
                16, 0, 0);
        }
    };

    // ---- compute tile i from buffer buf ----
    auto compute = [&](int buf, int i) {
        const int c0 = c_base + i * TCOLS;
        f32x16 acc;
#pragma unroll
        for (int q = 0; q < 16; ++q) acc[q] = 0.f;

#pragma unroll
        for (int rg = 0; rg < 4; ++rg) {
            short8v bh, bl;
#pragma unroll
            for (int j = 0; j < 8; ++j) {
                const float x = sT[buf][rg * 16 + kh + j][wv * 32 + cl];
                const HL r = split_bf16(x);
                bh[j] = r.h;
                bl[j] = r.l;
            }
            acc = __builtin_amdgcn_mfma_f32_32x32x16_bf16(aH[rg], bh, acc, 0, 0, 0);
            acc = __builtin_amdgcn_mfma_f32_32x32x16_bf16(aH[rg], bl, acc, 0, 0, 0);
            acc = __builtin_amdgcn_mfma_f32_32x32x16_bf16(aL[rg], bh, acc, 0, 0, 0);
        }

        // store: col = c0 + wv*32 + cl; row = (reg&3)+8*(reg>>2)+4*(lane>>5)
        float* __restrict__ ob = out + (size_t)(4 * (lane >> 5)) * ncol + c0 + wv * 32 + cl;
#pragma unroll
        for (int reg = 0; reg < 16; ++reg) {
            const int row = (reg & 3) + 8 * (reg >> 2);
            ob[(size_t)row * ncol] = acc[reg];
        }
    };

    // ---- main loop: double-buffered, counted vmcnt (T4: never drain) ----
    stage(0, 0);
    stage(1, 1);

#pragma unroll 1
    for (int i = 0; i < TILES; ++i) {
        const int buf = i & 1;
        // Wait until only the newest 8 VMEM ops (next tile's stage) remain:
        // guarantees this tile's stage + all older stores are complete.
        if (i + 1 < TILES) {
            asm volatile("s_waitcnt vmcnt(8)" ::: "memory");
        } else {
            asm volatile("s_waitcnt vmcnt(0)" ::: "memory");
        }
        __builtin_amdgcn_s_barrier();

        compute(buf, i);

        asm volatile("" ::: "memory");      // fence: no LDS reads past barrier
        __builtin_amdgcn_s_barrier();
        if (i + 2 < TILES) stage(buf, i + 2);
    }
}

extern "C" void kernel_launch(void* const* d_in, const int* in_sizes, int n_in,
                              void* d_out, int out_size, void* d_ws, size_t ws_size,
                              hipStream_t stream) {
    const float* wprobs = (const float*)d_in[0];
    const float* bprobs = (const float*)d_in[1];
    const int*   widx   = (const int*)d_in[2];
    const int*   bidx   = (const int*)d_in[3];
    const float* wbank  = (const float*)d_in[4];
    const float* bbank  = (const float*)d_in[5];
    float*       out    = (float*)d_out;

    ParameterMixture_86835648790543_kernel<<<GRID, BLK, 0, stream>>>(
        wprobs, bprobs, widx, bidx, wbank, bbank, out);
}

// Round 13
// 90.668 us; speedup vs baseline: 1.7387x; 1.1632x over previous
//
#include <hip/hip_runtime.h>
#include <hip/hip_bf16.h>

// ParameterMixture = thin GEMM C[32 x 1M] = P[32x64] @ W[64 x 1M], MFMA bf16
// split-compensated (Ph*Wh + Ph*Wl + Pl*Wh), layouts verified R6-R12.
//
// R13 = R9 chassis (GRID 512, dwordx4 streams, 93.7us) + two changes aimed
// at the queueing diagnosis (R10: pass-from-L3 == pass-from-HBM, pipes idle):
//  1. depth-4 rowgroup pipeline (named bufs A-D): 2x per-wave in-flight work
//     per inflated-latency quantum.
//  2. non-temporal load/store hints (wbank/C have zero intra-pass reuse;
//     R10 proved L3 hits buy no time, so losing absorption is free).

typedef __attribute__((ext_vector_type(8)))  short short8v;
typedef __attribute__((ext_vector_type(16))) float f32x16;
typedef __attribute__((ext_vector_type(4)))  float float4v;

constexpr int E = 64;
constexpr int K = 8;
constexpr int B = 32;
constexpr int OUT_DIM = 1024;

constexpr int NCOL     = 1024 * 1024;         // W cols
constexpr int BLK      = 256;
constexpr int GRID     = 512;                 // 2 blocks/CU, 8 waves/CU
constexpr int WAVES    = GRID * 4;            // 2048
constexpr int CPW      = NCOL / WAVES;        // 512 cols per wave
constexpr int CSTEP    = 128;                 // cols per step (4 tiles x 32)
constexpr int STEPS    = CPW / CSTEP;         // 4
constexpr int NRG      = STEPS * 4;           // 16 rowgroups per wave
constexpr int WM_ELEMS = B * NCOL;
constexpr int OB4      = OUT_DIM / 4;         // 256

struct HL { short h; short l; };

__device__ __forceinline__ HL split_bf16(float x) {
    const __hip_bfloat16 hb = __float2bfloat16(x);
    const float          hf = __bfloat162float(hb);
    const __hip_bfloat16 lb = __float2bfloat16(x - hf);
    HL r;
    r.h = __builtin_bit_cast(short, hb);
    r.l = __builtin_bit_cast(short, lb);
    return r;
}

__global__ __launch_bounds__(BLK, 2) void ParameterMixture_86835648790543_kernel(
    const float* __restrict__ wprobs,   // [B,K]
    const float* __restrict__ bprobs,   // [B,K]
    const int*   __restrict__ widx,     // [B,K]
    const int*   __restrict__ bidx,     // [B,K]
    const float* __restrict__ wbank,    // [E, NCOL]
    const float* __restrict__ bbank,    // [E,O]
    float*       __restrict__ out)      // [B*NCOL] ++ [B*O]
{
    const int bid  = blockIdx.x;
    const int t    = threadIdx.x;
    const int wv   = t >> 6;
    const int lane = t & 63;
    const int m    = lane & 31;         // A row (batch)
    const int kh   = (lane >> 5) * 8;   // k half-offset
    const int cl   = lane & 31;         // column-group index

    // ---- bias prologue on blocks 0..31 (tiny, fp32 exact) ----
    if (bid < 32) {
        const int tt   = bid * BLK + t;
        const int b    = tt / OB4;
        const int off4 = tt % OB4;
        const float4* __restrict__ bb4 = (const float4*)bbank;
        float4 a4 = make_float4(0.f, 0.f, 0.f, 0.f);
#pragma unroll
        for (int k = 0; k < K; ++k) {
            const float p = bprobs[b * K + k];
            const int   e = bidx[b * K + k];
            const float4 v = bb4[e * OB4 + off4];
            a4.x += p * v.x; a4.y += p * v.y;
            a4.z += p * v.z; a4.w += p * v.w;
        }
        ((float4*)(out + WM_ELEMS))[tt] = a4;
    }

    // ---- per-lane A-fragments (P in bf16 hi/lo, MFMA layout) ----
    float wp[K];
    int   wi[K];
#pragma unroll
    for (int k2 = 0; k2 < K; ++k2) {
        wp[k2] = wprobs[m * K + k2];
        wi[k2] = widx[m * K + k2];
    }
    short8v aH[4], aL[4];
#pragma unroll
    for (int s = 0; s < 4; ++s) {
#pragma unroll
        for (int j = 0; j < 8; ++j) {
            const int e = s * 16 + kh + j;
            float p = 0.f;
#pragma unroll
            for (int k2 = 0; k2 < K; ++k2)
                p += (wi[k2] == e) ? wp[k2] : 0.f;
            const HL r = split_bf16(p);
            aH[s][j] = r.h;
            aL[s][j] = r.l;
        }
    }

    const size_t ncol     = (size_t)NCOL;
    const int    wave_id  = bid * 4 + wv;
    const int    col_base = wave_id * CPW;

    // rowgroup g: step = g>>2, rows (g&3)*16 + kh + j, 8 nt float4 loads
    auto load_rg = [&](float4v (&w)[8], int g) {
        if (g > NRG - 1) g = NRG - 1;                 // tail clamp (harmless)
        const int c0 = col_base + (g >> 2) * CSTEP + 4 * cl;
        const int r0 = (g & 3) * 16 + kh;
        const float* __restrict__ base = wbank + c0;
#pragma unroll
        for (int j = 0; j < 8; ++j)
            w[j] = __builtin_nontemporal_load(
                (const float4v*)(base + (size_t)(r0 + j) * ncol));
    };

    float4v bufA[8], bufB[8], bufC[8], bufD[8];
    load_rg(bufA, 0);
    load_rg(bufB, 1);
    load_rg(bufC, 2);
    load_rg(bufD, 3);

#pragma unroll 1
    for (int step = 0; step < STEPS; ++step) {
        f32x16 acc[4];
#pragma unroll
        for (int tt2 = 0; tt2 < 4; ++tt2)
#pragma unroll
            for (int i = 0; i < 16; ++i) acc[tt2][i] = 0.f;

        const int g0 = step * 4;

        // one rowgroup: cvt 32 floats -> 4 tiles' bh/bl, then 12 MFMA
        auto compute_rg = [&](const float4v (&w)[8], int rg) {
            short8v bh[4], bl[4];
#pragma unroll
            for (int j = 0; j < 8; ++j) {
                const HL rx = split_bf16(w[j][0]);
                const HL ry = split_bf16(w[j][1]);
                const HL rz = split_bf16(w[j][2]);
                const HL rw = split_bf16(w[j][3]);
                bh[0][j] = rx.h; bl[0][j] = rx.l;
                bh[1][j] = ry.h; bl[1][j] = ry.l;
                bh[2][j] = rz.h; bl[2][j] = rz.l;
                bh[3][j] = rw.h; bl[3][j] = rw.l;
            }
#pragma unroll
            for (int tt2 = 0; tt2 < 4; ++tt2) {
                acc[tt2] = __builtin_amdgcn_mfma_f32_32x32x16_bf16(aH[rg], bh[tt2], acc[tt2], 0, 0, 0);
                acc[tt2] = __builtin_amdgcn_mfma_f32_32x32x16_bf16(aH[rg], bl[tt2], acc[tt2], 0, 0, 0);
                acc[tt2] = __builtin_amdgcn_mfma_f32_32x32x16_bf16(aL[rg], bh[tt2], acc[tt2], 0, 0, 0);
            }
        };

        // depth-4: each buf reissued for rg+4 right after consumption
        compute_rg(bufA, 0);  load_rg(bufA, g0 + 4);
        compute_rg(bufB, 1);  load_rg(bufB, g0 + 5);
        compute_rg(bufC, 2);  load_rg(bufC, g0 + 6);
        compute_rg(bufD, 3);  load_rg(bufD, g0 + 7);

        // store: lane cl holds cols c0+4cl..+3 of each row in its 4 accs
        const int c0 = col_base + step * CSTEP + 4 * cl;
        float* __restrict__ ob = out + c0 + (size_t)((lane >> 5) * 4) * ncol;
#pragma unroll
        for (int reg = 0; reg < 16; ++reg) {
            const int row = (reg & 3) + 8 * (reg >> 2);
            float4v v;
            v[0] = acc[0][reg]; v[1] = acc[1][reg];
            v[2] = acc[2][reg]; v[3] = acc[3][reg];
            __builtin_nontemporal_store(v, (float4v*)(ob + (size_t)row * ncol));
        }
    }
}

extern "C" void kernel_launch(void* const* d_in, const int* in_sizes, int n_in,
                              void* d_out, int out_size, void* d_ws, size_t ws_size,
                              hipStream_t stream) {
    const float* wprobs = (const float*)d_in[0];
    const float* bprobs = (const float*)d_in[1];
    const int*   widx   = (const int*)d_in[2];
    const int*   bidx   = (const int*)d_in[3];
    const float* wbank  = (const float*)d_in[4];
    const float* bbank  = (const float*)d_in[5];
    float*       out    = (float*)d_out;

    ParameterMixture_86835648790543_kernel<<<GRID, BLK, 0, stream>>>(
        wprobs, bprobs, widx, bidx, wbank, bbank, out);
}